// Round 7
// baseline (1354.766 us; speedup 1.0000x reference)
//
#include <hip/hip_runtime.h>
#include <cstdint>

// VAE fused forward, MI355X/gfx950 — f32 in / f32 out.
// N=65536 rows, IO=64, HID=60, LAT=32, T=8.
// Round 10 (resubmit — R6 bench was an infra failure, no data): revert R9's
// 2-traj decode (occupancy 23%, 302us). Restore R3 decode (206us, VALU 66%,
// occ 43%, VGPR exactly 64) with ONE change: __launch_bounds__(256,8) ->
// 8 blocks/CU (32 waves) instead of 4 (16). Weight s_loads are wave-uniform
// so K$ lines are shared across waves; more waves hide the SMEM waits that
// were the 34% VALU idle.
// Encoder: R7-exact (slot-split scalar weights) — residual analysis over
// rounds 1-5 shows encode+overhead is ~182-192us nearly structure-invariant;
// decode is the only responsive lever.
// RNG: JAX partitionable threefry, key (0,1): per flat index i,
//   bits = o0^o1 of threefry2x32(c0=0, c1=i);
//   u = max(lo,(f32(bits>>9|0x3F800000)-1)*2+lo), eps = sqrt(2)*erfinvf(u).
// Output (f32): traj[8][16][65536][4] @0 | mu[65536][32] @33554432 |
//   logvar[65536][32] @35651584 | prob[8][4096][16] @37748736 (== 0.125f).

#define TPB_A 256
#define NBLK_A 1024   // 64 rows/block x 4 slot-waves
#define TPB_B 256
#define NBLK_B 2048   // one thread per (n, t)

// JAX threefry2x32 with key (0,1): ks = {0, 1, 0^1^0x1BD11BDA = 0x1BD11BDB}
__device__ __forceinline__ void threefry2x32_01(uint32_t c0, uint32_t c1,
                                                uint32_t& o0, uint32_t& o1) {
  uint32_t x0 = c0;        // + ks0 (0)
  uint32_t x1 = c1 + 1u;   // + ks1 (1)
#define TFR(r) { x0 += x1; x1 = (x1 << (r)) | (x1 >> (32 - (r))); x1 ^= x0; }
  TFR(13) TFR(15) TFR(26) TFR(6)
  x0 += 1u;          x1 += 0x1BD11BDCu;   // ks1, ks2+1
  TFR(17) TFR(29) TFR(16) TFR(24)
  x0 += 0x1BD11BDBu; x1 += 2u;            // ks2, ks0+2
  TFR(13) TFR(15) TFR(26) TFR(6)
  /* + ks0=0 */      x1 += 4u;            // ks0, ks1+3
  TFR(17) TFR(29) TFR(16) TFR(24)
  x0 += 1u;          x1 += 0x1BD11BDFu;   // ks1, ks2+4
  TFR(13) TFR(15) TFR(26) TFR(6)
  x0 += 0x1BD11BDBu; x1 += 5u;            // ks2, ks0+5
#undef TFR
  o0 = x0; o1 = x1;
}

__device__ __forceinline__ uint32_t threefry_bits_partitionable(uint32_t idx) {
  uint32_t o0, o1;
  threefry2x32_01(0u, idx, o0, o1);
  return o0 ^ o1;
}

// jax.random.normal bit->float (f32): u in [lo,1), eps = sqrt(2)*erfinv(u)
__device__ __forceinline__ float bits_to_normal(uint32_t b) {
  const float lo = -0.99999994f;  // nextafter(-1,0)
  float f = __uint_as_float((b >> 9) | 0x3F800000u) - 1.0f;  // [0,1)
  float u = fmaxf(f * 2.0f + lo, lo);  // (hi-lo) rounds to exactly 2.0f
  return 1.41421356f * erfinvf(u);
}

// ---------------- Kernel A: encoder -> mu / logvar (R7-exact) ----------------
__global__ __launch_bounds__(TPB_A, 4) void vae_encode(
    const float* __restrict__ X,
    const float* __restrict__ w1, const float* __restrict__ b1,
    const float* __restrict__ wm, const float* __restrict__ bm,
    const float* __restrict__ wsd, const float* __restrict__ bsd,
    float* __restrict__ out) {
  const int tid = threadIdx.x;
  const int lane = tid & 63;
  const int slot = __builtin_amdgcn_readfirstlane(tid >> 6);  // 0..3, SGPR
  const int i0 = slot * 8;
  const int n = blockIdx.x * 64 + lane;

  // ---- x: own row, 16x float4 (coalesced within the wave) ----
  float x[64];
  {
    const float4* xr = (const float4*)(X + (size_t)n * 64);
#pragma unroll
    for (int q = 0; q < 16; ++q) {
      float4 v = xr[q];
      x[4 * q + 0] = v.x; x[4 * q + 1] = v.y;
      x[4 * q + 2] = v.z; x[4 * q + 3] = v.w;
    }
  }

  // ---- fused encoder + mean/std, slot-restricted scatter ----
  float mu[8], lv[8];
#pragma unroll
  for (int ii = 0; ii < 8; ++ii) { mu[ii] = bm[i0 + ii]; lv[ii] = bsd[i0 + ii]; }
  for (int j = 0; j < 60; ++j) {
    const float4* wr = (const float4*)(w1 + j * 64);  // uniform row
    float a0 = 0.f, a1 = 0.f, a2 = 0.f, a3 = 0.f;
#pragma unroll
    for (int q = 0; q < 16; ++q) {
      float4 w = wr[q];
      a0 = fmaf(w.x, x[4 * q + 0], a0);
      a1 = fmaf(w.y, x[4 * q + 1], a1);
      a2 = fmaf(w.z, x[4 * q + 2], a2);
      a3 = fmaf(w.w, x[4 * q + 3], a3);
    }
    float h = fmaxf((a0 + a1) + (a2 + a3) + b1[j], 0.f);
    const float* wmc = wm + i0 * 60 + j;   // uniform, stride-60 walk
    const float* wsc = wsd + i0 * 60 + j;
#pragma unroll
    for (int ii = 0; ii < 8; ++ii) {
      mu[ii] = fmaf(wmc[ii * 60], h, mu[ii]);
      lv[ii] = fmaf(wsc[ii * 60], h, lv[ii]);
    }
  }

  // ---- mu / logvar out: 32B contiguous per lane ----
  float4* muo = (float4*)(out + (size_t)33554432 + (size_t)n * 32 + i0);
  float4* lvo = (float4*)(out + (size_t)35651584 + (size_t)n * 32 + i0);
  float4 v0, v1, w0, w1v;
  v0.x = mu[0]; v0.y = mu[1]; v0.z = mu[2]; v0.w = mu[3];
  v1.x = mu[4]; v1.y = mu[5]; v1.z = mu[6]; v1.w = mu[7];
  w0.x = lv[0]; w0.y = lv[1]; w0.z = lv[2]; w0.w = lv[3];
  w1v.x = lv[4]; w1v.y = lv[5]; w1v.z = lv[6]; w1v.w = lv[7];
  muo[0] = v0; muo[1] = v1;
  lvo[0] = w0; lvo[1] = w1v;
}

// ---------------- Kernel B: one thread per (n, t) ----------------
// No LDS; dec1/dec2 weights + biases via wave-uniform scalar loads.
// launch_bounds(256,8): VGPR cap 64 (matches measured count) -> 32 waves/CU.
__global__ __launch_bounds__(TPB_B, 8) void vae_decode(
    const float* __restrict__ wd1, const float* __restrict__ bd1,
    const float* __restrict__ wd2, const float* __restrict__ bd2,
    float* __restrict__ out) {
  const int tid = threadIdx.x;
  const int g = blockIdx.x * TPB_B + tid;
  const int n = g & 65535;   // lane-consecutive n -> coalesced traj stores
  const int t = g >> 16;

  // ---- z = mu + eps * expf(0.5*lv)  (bit-identical op order) ----
  const float4* mur = (const float4*)(out + (size_t)33554432 + (size_t)n * 32);
  const float4* lvr = (const float4*)(out + (size_t)35651584 + (size_t)n * 32);
  const uint32_t cbase = (uint32_t)t * 2097152u + (uint32_t)n * 32u;
  float z[32];
#pragma unroll
  for (int gq = 0; gq < 8; ++gq) {
    float4 m4 = mur[gq];
    float4 v4 = lvr[gq];
    float s0 = expf(0.5f * v4.x), s1 = expf(0.5f * v4.y);
    float s2 = expf(0.5f * v4.z), s3 = expf(0.5f * v4.w);
    uint32_t c = cbase + (uint32_t)(4 * gq);
    z[4 * gq + 0] = fmaf(bits_to_normal(threefry_bits_partitionable(c + 0u)), s0, m4.x);
    z[4 * gq + 1] = fmaf(bits_to_normal(threefry_bits_partitionable(c + 1u)), s1, m4.y);
    z[4 * gq + 2] = fmaf(bits_to_normal(threefry_bits_partitionable(c + 2u)), s2, m4.z);
    z[4 * gq + 3] = fmaf(bits_to_normal(threefry_bits_partitionable(c + 3u)), s3, m4.w);
  }

  // ---- h3 = relu(dec1 @ z + bd1), row form ----
  float h3[60];
#pragma unroll
  for (int j = 0; j < 60; ++j) {
    const float* wj = wd1 + j * 32;   // uniform contiguous row (128B)
    float a = bd1[j];
#pragma unroll
    for (int l = 0; l < 32; ++l) a = fmaf(wj[l], z[l], a);
    h3[j] = fmaxf(a, 0.f);
  }

  // ---- dec2 + store: traj[t][hh][n][0:4], one float4 per (t,hh,n) ----
  {
    float4* trj = (float4*)out + (size_t)(t * 16) * 65536 + n;
    const float4* bd24 = (const float4*)bd2;
    for (int hh = 0; hh < 16; ++hh) {
      const float4* w0 = (const float4*)(wd2 + (hh * 4 + 0) * 60);
      const float4* w1r = (const float4*)(wd2 + (hh * 4 + 1) * 60);
      const float4* w2 = (const float4*)(wd2 + (hh * 4 + 2) * 60);
      const float4* w3 = (const float4*)(wd2 + (hh * 4 + 3) * 60);
      float a0 = 0.f, a1 = 0.f, a2 = 0.f, a3 = 0.f;
#pragma unroll
      for (int q = 0; q < 15; ++q) {
        float4 wa = w0[q], wb = w1r[q], wc = w2[q], wdv = w3[q];
        float h0 = h3[4 * q + 0], hv1 = h3[4 * q + 1];
        float hv2 = h3[4 * q + 2], hv3 = h3[4 * q + 3];
        a0 = fmaf(wa.x, h0, a0); a0 = fmaf(wa.y, hv1, a0);
        a0 = fmaf(wa.z, hv2, a0); a0 = fmaf(wa.w, hv3, a0);
        a1 = fmaf(wb.x, h0, a1); a1 = fmaf(wb.y, hv1, a1);
        a1 = fmaf(wb.z, hv2, a1); a1 = fmaf(wb.w, hv3, a1);
        a2 = fmaf(wc.x, h0, a2); a2 = fmaf(wc.y, hv1, a2);
        a2 = fmaf(wc.z, hv2, a2); a2 = fmaf(wc.w, hv3, a2);
        a3 = fmaf(wdv.x, h0, a3); a3 = fmaf(wdv.y, hv1, a3);
        a3 = fmaf(wdv.z, hv2, a3); a3 = fmaf(wdv.w, hv3, a3);
      }
      float4 bb = bd24[hh];
      float4 o;
      o.x = a0 + bb.x; o.y = a1 + bb.y; o.z = a2 + bb.z; o.w = a3 + bb.w;
      trj[(size_t)hh * 65536] = o;
    }
  }

  // ---- prob_list: exactly 1/8 ----
  out[(size_t)37748736 + (size_t)t * 65536 + (size_t)n] = 0.125f;
}

extern "C" void kernel_launch(void* const* d_in, const int* in_sizes, int n_in,
                              void* d_out, int out_size, void* d_ws, size_t ws_size,
                              hipStream_t stream) {
  const float* X   = (const float*)d_in[0];
  // d_in[1] = num_traj (int scalar, fixed == 8)
  const float* w1  = (const float*)d_in[2];
  const float* b1  = (const float*)d_in[3];
  const float* wm  = (const float*)d_in[4];
  const float* bm  = (const float*)d_in[5];
  const float* wsd = (const float*)d_in[6];
  const float* bsd = (const float*)d_in[7];
  const float* wd1 = (const float*)d_in[8];
  const float* bd1 = (const float*)d_in[9];
  const float* wd2 = (const float*)d_in[10];
  const float* bd2 = (const float*)d_in[11];

  vae_encode<<<NBLK_A, TPB_A, 0, stream>>>(X, w1, b1, wm, bm, wsd, bsd,
                                           (float*)d_out);
  vae_decode<<<NBLK_B, TPB_B, 0, stream>>>(wd1, bd1, wd2, bd2, (float*)d_out);
}

// Round 9
// 432.240 us; speedup vs baseline: 3.1343x; 3.1343x over previous
//
#include <hip/hip_runtime.h>
#include <cstdint>

// VAE fused forward, MI355X/gfx950 — f32 in / f32 out.
// N=65536 rows, IO=64, HID=60, LAT=32, T=8.
// Round 11 (resubmit — R8 bench was an infra failure, no data): R7's (256,8)
// forced VGPR 32 -> scratch spill (FETCH 2.9GB), 1168us. Decode reverted to
// the proven R3 config ((256,4), VGPR 64, 206us) with ONE change: erfinvf
// (libm, branch/division-heavy, ~both paths taken under divergence) replaced
// by the XLA ErfInv32 polynomial (Giles) — the EXACT algorithm
// jax.random.normal uses, so eps becomes bit-identical to the reference
// while cutting the dominant per-thread VALU cost (32 calls).
// Encoder: R7-exact slot-split scalar-weight version.
// RNG: JAX partitionable threefry, key (0,1): per flat index i,
//   bits = o0^o1 of threefry2x32(c0=0, c1=i);
//   u = max(lo,(f32(bits>>9|0x3F800000)-1)*2+lo), eps = sqrt(2)*ErfInv32(u).
// Output (f32): traj[8][16][65536][4] @0 | mu[65536][32] @33554432 |
//   logvar[65536][32] @35651584 | prob[8][4096][16] @37748736 (== 0.125f).

#define TPB_A 256
#define NBLK_A 1024   // 64 rows/block x 4 slot-waves
#define TPB_B 256
#define NBLK_B 2048   // one thread per (n, t)

// JAX threefry2x32 with key (0,1): ks = {0, 1, 0^1^0x1BD11BDA = 0x1BD11BDB}
__device__ __forceinline__ void threefry2x32_01(uint32_t c0, uint32_t c1,
                                                uint32_t& o0, uint32_t& o1) {
  uint32_t x0 = c0;        // + ks0 (0)
  uint32_t x1 = c1 + 1u;   // + ks1 (1)
#define TFR(r) { x0 += x1; x1 = (x1 << (r)) | (x1 >> (32 - (r))); x1 ^= x0; }
  TFR(13) TFR(15) TFR(26) TFR(6)
  x0 += 1u;          x1 += 0x1BD11BDCu;   // ks1, ks2+1
  TFR(17) TFR(29) TFR(16) TFR(24)
  x0 += 0x1BD11BDBu; x1 += 2u;            // ks2, ks0+2
  TFR(13) TFR(15) TFR(26) TFR(6)
  /* + ks0=0 */      x1 += 4u;            // ks0, ks1+3
  TFR(17) TFR(29) TFR(16) TFR(24)
  x0 += 1u;          x1 += 0x1BD11BDFu;   // ks1, ks2+4
  TFR(13) TFR(15) TFR(26) TFR(6)
  x0 += 0x1BD11BDBu; x1 += 5u;            // ks2, ks0+5
#undef TFR
  o0 = x0; o1 = x1;
}

__device__ __forceinline__ uint32_t threefry_bits_partitionable(uint32_t idx) {
  uint32_t o0, o1;
  threefry2x32_01(0u, idx, o0, o1);
  return o0 ^ o1;
}

// XLA ErfInv32 (Giles) — the exact polynomial JAX lowers erf_inv to on f32.
__device__ __forceinline__ float erfinv_xla(float x) {
  float w = -log1pf(-x * x);
  float p;
  if (w < 5.0f) {
    w = w - 2.5f;
    p = 2.81022636e-08f;
    p = fmaf(p, w, 3.43273939e-07f);
    p = fmaf(p, w, -3.5233877e-06f);
    p = fmaf(p, w, -4.39150654e-06f);
    p = fmaf(p, w, 0.00021858087f);
    p = fmaf(p, w, -0.00125372503f);
    p = fmaf(p, w, -0.00417768164f);
    p = fmaf(p, w, 0.246640727f);
    p = fmaf(p, w, 1.50140941f);
  } else {
    w = sqrtf(w) - 3.0f;
    p = -0.000200214257f;
    p = fmaf(p, w, 0.000100950558f);
    p = fmaf(p, w, 0.00134934322f);
    p = fmaf(p, w, -0.00367342844f);
    p = fmaf(p, w, 0.00573950773f);
    p = fmaf(p, w, -0.0076224613f);
    p = fmaf(p, w, 0.00943887047f);
    p = fmaf(p, w, 1.00167406f);
    p = fmaf(p, w, 2.83297682f);
  }
  return p * x;
}

// jax.random.normal bit->float (f32): u in [lo,1), eps = sqrt(2)*erfinv(u)
__device__ __forceinline__ float bits_to_normal(uint32_t b) {
  const float lo = -0.99999994f;  // nextafter(-1,0)
  float f = __uint_as_float((b >> 9) | 0x3F800000u) - 1.0f;  // [0,1)
  float u = fmaxf(f * 2.0f + lo, lo);  // (hi-lo) rounds to exactly 2.0f
  return 1.41421356f * erfinv_xla(u);
}

// ---------------- Kernel A: encoder -> mu / logvar (R7-exact) ----------------
__global__ __launch_bounds__(TPB_A, 4) void vae_encode(
    const float* __restrict__ X,
    const float* __restrict__ w1, const float* __restrict__ b1,
    const float* __restrict__ wm, const float* __restrict__ bm,
    const float* __restrict__ wsd, const float* __restrict__ bsd,
    float* __restrict__ out) {
  const int tid = threadIdx.x;
  const int lane = tid & 63;
  const int slot = __builtin_amdgcn_readfirstlane(tid >> 6);  // 0..3, SGPR
  const int i0 = slot * 8;
  const int n = blockIdx.x * 64 + lane;

  // ---- x: own row, 16x float4 (coalesced within the wave) ----
  float x[64];
  {
    const float4* xr = (const float4*)(X + (size_t)n * 64);
#pragma unroll
    for (int q = 0; q < 16; ++q) {
      float4 v = xr[q];
      x[4 * q + 0] = v.x; x[4 * q + 1] = v.y;
      x[4 * q + 2] = v.z; x[4 * q + 3] = v.w;
    }
  }

  // ---- fused encoder + mean/std, slot-restricted scatter ----
  float mu[8], lv[8];
#pragma unroll
  for (int ii = 0; ii < 8; ++ii) { mu[ii] = bm[i0 + ii]; lv[ii] = bsd[i0 + ii]; }
  for (int j = 0; j < 60; ++j) {
    const float4* wr = (const float4*)(w1 + j * 64);  // uniform row
    float a0 = 0.f, a1 = 0.f, a2 = 0.f, a3 = 0.f;
#pragma unroll
    for (int q = 0; q < 16; ++q) {
      float4 w = wr[q];
      a0 = fmaf(w.x, x[4 * q + 0], a0);
      a1 = fmaf(w.y, x[4 * q + 1], a1);
      a2 = fmaf(w.z, x[4 * q + 2], a2);
      a3 = fmaf(w.w, x[4 * q + 3], a3);
    }
    float h = fmaxf((a0 + a1) + (a2 + a3) + b1[j], 0.f);
    const float* wmc = wm + i0 * 60 + j;   // uniform, stride-60 walk
    const float* wsc = wsd + i0 * 60 + j;
#pragma unroll
    for (int ii = 0; ii < 8; ++ii) {
      mu[ii] = fmaf(wmc[ii * 60], h, mu[ii]);
      lv[ii] = fmaf(wsc[ii * 60], h, lv[ii]);
    }
  }

  // ---- mu / logvar out: 32B contiguous per lane ----
  float4* muo = (float4*)(out + (size_t)33554432 + (size_t)n * 32 + i0);
  float4* lvo = (float4*)(out + (size_t)35651584 + (size_t)n * 32 + i0);
  float4 v0, v1, w0, w1v;
  v0.x = mu[0]; v0.y = mu[1]; v0.z = mu[2]; v0.w = mu[3];
  v1.x = mu[4]; v1.y = mu[5]; v1.z = mu[6]; v1.w = mu[7];
  w0.x = lv[0]; w0.y = lv[1]; w0.z = lv[2]; w0.w = lv[3];
  w1v.x = lv[4]; w1v.y = lv[5]; w1v.z = lv[6]; w1v.w = lv[7];
  muo[0] = v0; muo[1] = v1;
  lvo[0] = w0; lvo[1] = w1v;
}

// ---------------- Kernel B: one thread per (n, t) ----------------
// No LDS; dec1/dec2 weights + biases via wave-uniform scalar loads.
// (256,4): proven config — VGPR 64, no spill, 206us baseline.
__global__ __launch_bounds__(TPB_B, 4) void vae_decode(
    const float* __restrict__ wd1, const float* __restrict__ bd1,
    const float* __restrict__ wd2, const float* __restrict__ bd2,
    float* __restrict__ out) {
  const int tid = threadIdx.x;
  const int g = blockIdx.x * TPB_B + tid;
  const int n = g & 65535;   // lane-consecutive n -> coalesced traj stores
  const int t = g >> 16;

  // ---- z = mu + eps * expf(0.5*lv)  (bit-identical op order) ----
  const float4* mur = (const float4*)(out + (size_t)33554432 + (size_t)n * 32);
  const float4* lvr = (const float4*)(out + (size_t)35651584 + (size_t)n * 32);
  const uint32_t cbase = (uint32_t)t * 2097152u + (uint32_t)n * 32u;
  float z[32];
#pragma unroll
  for (int gq = 0; gq < 8; ++gq) {
    float4 m4 = mur[gq];
    float4 v4 = lvr[gq];
    float s0 = expf(0.5f * v4.x), s1 = expf(0.5f * v4.y);
    float s2 = expf(0.5f * v4.z), s3 = expf(0.5f * v4.w);
    uint32_t c = cbase + (uint32_t)(4 * gq);
    z[4 * gq + 0] = fmaf(bits_to_normal(threefry_bits_partitionable(c + 0u)), s0, m4.x);
    z[4 * gq + 1] = fmaf(bits_to_normal(threefry_bits_partitionable(c + 1u)), s1, m4.y);
    z[4 * gq + 2] = fmaf(bits_to_normal(threefry_bits_partitionable(c + 2u)), s2, m4.z);
    z[4 * gq + 3] = fmaf(bits_to_normal(threefry_bits_partitionable(c + 3u)), s3, m4.w);
  }

  // ---- h3 = relu(dec1 @ z + bd1), row form ----
  float h3[60];
#pragma unroll
  for (int j = 0; j < 60; ++j) {
    const float* wj = wd1 + j * 32;   // uniform contiguous row (128B)
    float a = bd1[j];
#pragma unroll
    for (int l = 0; l < 32; ++l) a = fmaf(wj[l], z[l], a);
    h3[j] = fmaxf(a, 0.f);
  }

  // ---- dec2 + store: traj[t][hh][n][0:4], one float4 per (t,hh,n) ----
  {
    float4* trj = (float4*)out + (size_t)(t * 16) * 65536 + n;
    const float4* bd24 = (const float4*)bd2;
    for (int hh = 0; hh < 16; ++hh) {
      const float4* w0 = (const float4*)(wd2 + (hh * 4 + 0) * 60);
      const float4* w1r = (const float4*)(wd2 + (hh * 4 + 1) * 60);
      const float4* w2 = (const float4*)(wd2 + (hh * 4 + 2) * 60);
      const float4* w3 = (const float4*)(wd2 + (hh * 4 + 3) * 60);
      float a0 = 0.f, a1 = 0.f, a2 = 0.f, a3 = 0.f;
#pragma unroll
      for (int q = 0; q < 15; ++q) {
        float4 wa = w0[q], wb = w1r[q], wc = w2[q], wdv = w3[q];
        float h0 = h3[4 * q + 0], hv1 = h3[4 * q + 1];
        float hv2 = h3[4 * q + 2], hv3 = h3[4 * q + 3];
        a0 = fmaf(wa.x, h0, a0); a0 = fmaf(wa.y, hv1, a0);
        a0 = fmaf(wa.z, hv2, a0); a0 = fmaf(wa.w, hv3, a0);
        a1 = fmaf(wb.x, h0, a1); a1 = fmaf(wb.y, hv1, a1);
        a1 = fmaf(wb.z, hv2, a1); a1 = fmaf(wb.w, hv3, a1);
        a2 = fmaf(wc.x, h0, a2); a2 = fmaf(wc.y, hv1, a2);
        a2 = fmaf(wc.z, hv2, a2); a2 = fmaf(wc.w, hv3, a2);
        a3 = fmaf(wdv.x, h0, a3); a3 = fmaf(wdv.y, hv1, a3);
        a3 = fmaf(wdv.z, hv2, a3); a3 = fmaf(wdv.w, hv3, a3);
      }
      float4 bb = bd24[hh];
      float4 o;
      o.x = a0 + bb.x; o.y = a1 + bb.y; o.z = a2 + bb.z; o.w = a3 + bb.w;
      trj[(size_t)hh * 65536] = o;
    }
  }

  // ---- prob_list: exactly 1/8 ----
  out[(size_t)37748736 + (size_t)t * 65536 + (size_t)n] = 0.125f;
}

extern "C" void kernel_launch(void* const* d_in, const int* in_sizes, int n_in,
                              void* d_out, int out_size, void* d_ws, size_t ws_size,
                              hipStream_t stream) {
  const float* X   = (const float*)d_in[0];
  // d_in[1] = num_traj (int scalar, fixed == 8)
  const float* w1  = (const float*)d_in[2];
  const float* b1  = (const float*)d_in[3];
  const float* wm  = (const float*)d_in[4];
  const float* bm  = (const float*)d_in[5];
  const float* wsd = (const float*)d_in[6];
  const float* bsd = (const float*)d_in[7];
  const float* wd1 = (const float*)d_in[8];
  const float* bd1 = (const float*)d_in[9];
  const float* wd2 = (const float*)d_in[10];
  const float* bd2 = (const float*)d_in[11];

  vae_encode<<<NBLK_A, TPB_A, 0, stream>>>(X, w1, b1, wm, bm, wsd, bsd,
                                           (float*)d_out);
  vae_decode<<<NBLK_B, TPB_B, 0, stream>>>(wd1, bd1, wd2, bd2, (float*)d_out);
}